// Round 9
// baseline (32.116 us; speedup 1.0000x reference)
//
#include <hip/hip_runtime.h>

// RegionAttention: bin 8M landmarks into a 512x512 grid; out[i] = enhanced[i]
// if any landmark falls in bin i else 1.0f.
//
// Round 9: DIAGNOSTIC. Exact R5 structure (best: 20.07us), but bin_lds_kernel
// launched TWICE. bin is idempotent (recomputes identical region contents via
// plain stores), so this is correctness-preserving and measures bin+gap
// directly: T9 - T5 = bin + gap. Splits "bin_core ~15us (in-kernel slack)"
// vs "bin ~10.5us (slack is dispatch consts/L2-WBINV)" — five structural
// levers (R4 occ, R5 MLP, R6 coop, R7 merge, R8 atomics) were null/negative,
// so measure before optimizing further (skill: ablate empirically, m177).

#define N_LANDMARKS 8388608
#define N_BINS      262144            // 512*512
#define GRID_COLS   512
#define NWORDS      (N_BINS / 32)     // 8192 dwords = 32 KB bitmask
#define P1_BLOCKS   256
#define P1_THREADS  1024
#define P1_ITERS    16                // (N_LANDMARKS/2) / (P1_BLOCKS*P1_THREADS)

// --- pass 1: bin into per-block LDS bitmask, dump coalesced ------------------

__global__ __launch_bounds__(P1_THREADS)
void bin_lds_kernel(const float4* __restrict__ lm2,
                    unsigned int* __restrict__ regions) {
    __shared__ unsigned int mask[NWORDS];
    const int tid = threadIdx.x;

    #pragma unroll
    for (int w = tid; w < NWORDS; w += P1_THREADS) mask[w] = 0u;
    __syncthreads();

    const int total = P1_BLOCKS * P1_THREADS;          // 262144 threads
    const int base  = blockIdx.x * P1_THREADS + tid;

    float4 buf[P1_ITERS];
    #pragma unroll
    for (int k = 0; k < P1_ITERS; ++k)
        buf[k] = lm2[base + k * total];

    #pragma unroll
    for (int k = 0; k < P1_ITERS; ++k) {
        float4 v = buf[k];                             // (x0,y0,x1,y1)
        int c0 = min((int)(v.x * 0.0625f), GRID_COLS - 1);
        int r0 = min((int)(v.y * 0.0625f), GRID_COLS - 1);
        int c1 = min((int)(v.z * 0.0625f), GRID_COLS - 1);
        int r1 = min((int)(v.w * 0.0625f), GRID_COLS - 1);
        unsigned int i0 = (unsigned int)(r0 * GRID_COLS + c0);
        unsigned int i1 = (unsigned int)(r1 * GRID_COLS + c1);
        atomicOr(&mask[i0 >> 5], 1u << (i0 & 31));     // ds_or_b32, no return
        atomicOr(&mask[i1 >> 5], 1u << (i1 & 31));
    }
    __syncthreads();

    unsigned int* dst = regions + (size_t)blockIdx.x * NWORDS;
    #pragma unroll
    for (int w = tid; w < NWORDS; w += P1_THREADS) dst[w] = mask[w];
}

// --- pass 2: OR the 256 regions (8-way split), blend with enhanced_weight ----

__global__ __launch_bounds__(256)
void merge_blend_kernel(const unsigned int* __restrict__ regions,
                        const float4* __restrict__ ew4,
                        float4* __restrict__ out4) {
    __shared__ unsigned int part[8][33];               // +1 pad: conflict-free reduce
    __shared__ unsigned int merged[32];

    const int t   = threadIdx.x;
    const int wl  = t & 31;                            // word within block
    const int seg = t >> 5;                            // region segment, 0..7
    const int w   = blockIdx.x * 32 + wl;              // global word index

    const unsigned int* p = regions + (size_t)seg * 32 * NWORDS + w;
    unsigned int m = 0u;
    #pragma unroll
    for (int b = 0; b < 32; ++b)
        m |= p[(size_t)b * NWORDS];
    part[seg][wl] = m;
    __syncthreads();

    if (t < 32) {
        unsigned int mm = part[0][t];
        #pragma unroll
        for (int s = 1; s < 8; ++s) mm |= part[s][t];
        merged[t] = mm;
    }
    __syncthreads();

    const int g4 = blockIdx.x * 256 + t;
    const unsigned int mw = merged[t >> 3];
    const int sh = (t & 7) * 4;
    float4 e = ew4[g4];
    float4 r;
    r.x = ((mw >> (sh + 0)) & 1u) ? e.x : 1.0f;
    r.y = ((mw >> (sh + 1)) & 1u) ? e.y : 1.0f;
    r.z = ((mw >> (sh + 2)) & 1u) ? e.z : 1.0f;
    r.w = ((mw >> (sh + 3)) & 1u) ? e.w : 1.0f;
    out4[g4] = r;
}

extern "C" void kernel_launch(void* const* d_in, const int* in_sizes, int n_in,
                              void* d_out, int out_size, void* d_ws, size_t ws_size,
                              hipStream_t stream) {
    const float4* lm2 = (const float4*)d_in[0];
    const float*  ew  = (const float*)d_in[1];
    float* out        = (float*)d_out;

    const size_t regions_bytes = (size_t)P1_BLOCKS * NWORDS * sizeof(unsigned int); // 8 MB
    unsigned int* regions = (unsigned int*)d_ws;   // ws is ~268 MB, always sufficient

    // DIAGNOSTIC: bin launched twice (idempotent). T9 - T5 = bin + gap.
    bin_lds_kernel<<<P1_BLOCKS, P1_THREADS, 0, stream>>>(lm2, regions);
    bin_lds_kernel<<<P1_BLOCKS, P1_THREADS, 0, stream>>>(lm2, regions);
    merge_blend_kernel<<<NWORDS / 32, 256, 0, stream>>>(
        regions, (const float4*)ew, (float4*)out);
    (void)regions_bytes; (void)ws_size; (void)in_sizes; (void)n_in; (void)out_size;
}

// Round 11
// 20.387 us; speedup vs baseline: 1.5753x; 1.5753x over previous
//
#include <hip/hip_runtime.h>

// RegionAttention: bin 8M landmarks into a 512x512 grid; out[i] = enhanced[i]
// if any landmark falls in bin i else 1.0f.
//
// Round 11 = Round 10 with compile fix: __builtin_nontemporal_{store,load}
// require native clang vector types, not HIP_vector_type (uint4). Use
// ext_vector_type(4) unsigned for the NT dump.
// Theory (R9 diag): bin+gap = 12.05us -> merge+fixed ~8us; slack = 8MB dirty
// per-XCD L2 flushed at bin->merge boundary + merge re-read.
//  - bin dump via nontemporal streaming stores (don't dirty L2)
//  - merge region loads nontemporal
//  - merge at 512 thr/block (8 waves/CU), 16 segs x 16 regions, float2 blend.
// Ledger: R4 occ null | R5 MLP null | R6 coop -45us | R7 merge-width null |
// R8 global-atomics -7us | R9 diag bin+gap=12.05.

typedef unsigned int uintv4 __attribute__((ext_vector_type(4)));

#define N_LANDMARKS 8388608
#define N_BINS      262144            // 512*512
#define GRID_COLS   512
#define NWORDS      (N_BINS / 32)     // 8192 dwords = 32 KB bitmask
#define NQUADS      (NWORDS / 4)      // 2048 16B-quads per region
#define P1_BLOCKS   256
#define P1_THREADS  1024
#define P1_ITERS    16                // (N_LANDMARKS/2) / (P1_BLOCKS*P1_THREADS)

// --- pass 1: bin into per-block LDS bitmask, NT dump --------------------------

__global__ __launch_bounds__(P1_THREADS)
void bin_lds_kernel(const float4* __restrict__ lm2,
                    unsigned int* __restrict__ regions) {
    __shared__ unsigned int mask[NWORDS];
    const int tid = threadIdx.x;

    uintv4* mask4 = (uintv4*)mask;
    #pragma unroll
    for (int w = tid; w < NQUADS; w += P1_THREADS)
        mask4[w] = (uintv4){0u, 0u, 0u, 0u};
    __syncthreads();

    const int total = P1_BLOCKS * P1_THREADS;          // 262144 threads
    const int base  = blockIdx.x * P1_THREADS + tid;

    float4 buf[P1_ITERS];
    #pragma unroll
    for (int k = 0; k < P1_ITERS; ++k)
        buf[k] = lm2[base + k * total];

    #pragma unroll
    for (int k = 0; k < P1_ITERS; ++k) {
        float4 v = buf[k];                             // (x0,y0,x1,y1)
        int c0 = min((int)(v.x * 0.0625f), GRID_COLS - 1);
        int r0 = min((int)(v.y * 0.0625f), GRID_COLS - 1);
        int c1 = min((int)(v.z * 0.0625f), GRID_COLS - 1);
        int r1 = min((int)(v.w * 0.0625f), GRID_COLS - 1);
        unsigned int i0 = (unsigned int)(r0 * GRID_COLS + c0);
        unsigned int i1 = (unsigned int)(r1 * GRID_COLS + c1);
        atomicOr(&mask[i0 >> 5], 1u << (i0 & 31));     // ds_or_b32, no return
        atomicOr(&mask[i1 >> 5], 1u << (i1 & 31));
    }
    __syncthreads();

    // NT streaming dump: avoid leaving 8MB dirty in per-XCD L2s for the
    // boundary WB-INV to flush.
    uintv4* dst4 = (uintv4*)(regions + (size_t)blockIdx.x * NWORDS);
    #pragma unroll
    for (int w = tid; w < NQUADS; w += P1_THREADS)
        __builtin_nontemporal_store(mask4[w], &dst4[w]);
}

// --- pass 2: OR the 256 regions (16-way split), blend ------------------------
// 256 blocks x 512 thr (8 waves/CU). Block owns 32 words = 1024 bins.
// seg s (0..15) ORs regions s*16..s*16+15; lanes wl 0..31 read 128B contiguous.

__global__ __launch_bounds__(512)
void merge_blend_kernel(const unsigned int* __restrict__ regions,
                        const float2* __restrict__ ew2,
                        float2* __restrict__ out2) {
    __shared__ unsigned int part[16][33];              // +1 pad
    __shared__ unsigned int merged[32];

    const int t   = threadIdx.x;                       // 0..511
    const int wl  = t & 31;                            // word within block
    const int seg = t >> 5;                            // 0..15
    const int w   = blockIdx.x * 32 + wl;              // global word index

    const unsigned int* p = regions + (size_t)seg * 16 * NWORDS + w;
    unsigned int m = 0u;
    #pragma unroll
    for (int b = 0; b < 16; ++b)
        m |= __builtin_nontemporal_load(&p[(size_t)b * NWORDS]);
    part[seg][wl] = m;
    __syncthreads();

    if (t < 32) {
        unsigned int mm = part[0][t];
        #pragma unroll
        for (int s = 1; s < 16; ++s) mm |= part[s][t];
        merged[t] = mm;
    }
    __syncthreads();

    // blend: 1024 bins/block = 512 float2; thread t -> bins 2t, 2t+1 (local)
    const int g2 = blockIdx.x * 512 + t;
    const unsigned int mw = merged[t >> 4];
    const int sh = (t & 15) * 2;
    float2 e = ew2[g2];
    float2 r;
    r.x = ((mw >> (sh + 0)) & 1u) ? e.x : 1.0f;
    r.y = ((mw >> (sh + 1)) & 1u) ? e.y : 1.0f;
    out2[g2] = r;
}

extern "C" void kernel_launch(void* const* d_in, const int* in_sizes, int n_in,
                              void* d_out, int out_size, void* d_ws, size_t ws_size,
                              hipStream_t stream) {
    const float4* lm2 = (const float4*)d_in[0];
    const float*  ew  = (const float*)d_in[1];
    float* out        = (float*)d_out;

    unsigned int* regions = (unsigned int*)d_ws;       // 8 MB; ws is ~268 MB

    bin_lds_kernel<<<P1_BLOCKS, P1_THREADS, 0, stream>>>(lm2, regions);
    merge_blend_kernel<<<NWORDS / 32, 512, 0, stream>>>(
        regions, (const float2*)ew, (float2*)out);

    (void)in_sizes; (void)n_in; (void)out_size; (void)ws_size;
}